// Round 6
// baseline (816.810 us; speedup 1.0000x reference)
//
#include <hip/hip_runtime.h>

#define N_NODES 50000
#define N_EDGES 800000
#define F_INP   32
#define HDIM    64
#define EDIM    16
#define COUT    40
#define NGRAPH  64

// ---------------------------------------------------------------- sort by dst
__global__ void hist_kernel(const int* __restrict__ dst, int* __restrict__ cnt, int E) {
    int e = blockIdx.x * 256 + threadIdx.x;
    if (e < E) atomicAdd(&cnt[dst[e]], 1);
}

// single-block exclusive scan of cnt[0..n) -> offsets/cursor (replaces 3-kernel chain)
__global__ __launch_bounds__(1024) void scan_all_kernel(const int* __restrict__ cnt,
                                                        int* __restrict__ offsets,
                                                        int* __restrict__ cursor, int n) {
    __shared__ int part[1024];
    int tid = threadIdx.x;
    const int PER = (n + 1023) / 1024;       // 49
    int beg = tid * PER;
    int end = beg + PER; if (end > n) end = n;
    int s = 0;
    for (int i = beg; i < end; i++) s += cnt[i];
    part[tid] = s;
    __syncthreads();
    for (int off = 1; off < 1024; off <<= 1) {   // Hillis-Steele inclusive
        int x = (tid >= off) ? part[tid - off] : 0;
        __syncthreads();
        part[tid] += x;
        __syncthreads();
    }
    int run = part[tid] - s;                 // exclusive base of this range
    for (int i = beg; i < end; i++) {
        offsets[i] = run; cursor[i] = run;
        run += cnt[i];
    }
    if (tid == 1023) offsets[n] = run;       // total = E
}

// materialize per-sorted-position edge id, dst, and src
__global__ void scatter_kernel(const int* __restrict__ dst, const int* __restrict__ src,
                               int* __restrict__ cursor, int* __restrict__ sorted,
                               int* __restrict__ dsts, int* __restrict__ srcs, int E) {
    int e = blockIdx.x * 256 + threadIdx.x;
    if (e < E) {
        int d = dst[e];
        int p = atomicAdd(&cursor[d], 1);
        sorted[p] = e;
        dsts[p]   = d;
        srcs[p]   = src[e];
    }
}

// batch is sorted ascending; find graph start offsets
__global__ void gstart_kernel(const int* __restrict__ batch, int* __restrict__ gstart,
                              int N, int G) {
    int n = blockIdx.x * 256 + threadIdx.x;
    if (n >= N) return;
    int g  = batch[n];
    int gp = (n == 0) ? -1 : batch[n - 1];
    for (int gg = gp + 1; gg <= g; gg++) gstart[gg] = n;
    if (n == N - 1) {
        for (int gg = g + 1; gg <= G; gg++) gstart[gg] = N;
    }
}

// ---------------------------------------------------------------- input linear
// Grid-stride (256 blocks); fused BN-stats epilogue -> statsA0.
__global__ __launch_bounds__(256) void lin_in_kernel(
        const float* __restrict__ x, const float* __restrict__ W,
        const float* __restrict__ b, float* __restrict__ h,
        float* __restrict__ stats, int N) {
    int tid = threadIdx.x;
    int c = tid & 63;
    float w[F_INP];
#pragma unroll
    for (int k = 0; k < F_INP; k++) w[k] = W[k * HDIM + c];
    float bcv = b[c];
    float s = 0.f, ss = 0.f;
    for (int node = blockIdx.x * 4 + (tid >> 6); node < N; node += 1024) {
        const float4* xr = (const float4*)(x + (size_t)node * F_INP);
        float acc = bcv;
#pragma unroll
        for (int k4 = 0; k4 < F_INP / 4; k4++) {
            float4 xv = xr[k4];
            acc += xv.x * w[k4 * 4 + 0] + xv.y * w[k4 * 4 + 1]
                 + xv.z * w[k4 * 4 + 2] + xv.w * w[k4 * 4 + 3];
        }
        h[(size_t)node * HDIM + c] = acc;
        s += acc; ss += acc * acc;
    }
    __shared__ float ls[256], lss[256];
    ls[tid] = s; lss[tid] = ss;
    __syncthreads();
    if (tid < 64) {
        float ts  = ls[tid] + ls[tid + 64] + ls[tid + 128] + ls[tid + 192];
        float tss = lss[tid] + lss[tid + 64] + lss[tid + 128] + lss[tid + 192];
        atomicAdd(&stats[c], ts);
        atomicAdd(&stats[HDIM + c], tss);
    }
}

// ---------------------------------------------------------------- edge-parallel aggregation
// One wave per 64 contiguous dst-sorted positions; ONE EDGE PER LANE.
// launch_bounds(256, 4): VGPR budget 128/thread so the working set
// (w[16] + a[16] + hv[8] + scalars) stays register-resident. Round-5 counters
// showed VGPR_Count=36 -> scratch cycling: ~132 VALU inst/edge vs ~48 written,
// and 58 MB of FETCH above compulsory (~18 dwords reloaded/edge).
__global__ __launch_bounds__(256, 4) void edge_agg_kernel(
        const float* __restrict__ h, const float* __restrict__ ea,
        const int* __restrict__ sorted, const int* __restrict__ dsts,
        const int* __restrict__ srcs,
        const float* __restrict__ We, const float* __restrict__ be,
        const float* __restrict__ tptr, const float* __restrict__ stats,
        const float* __restrict__ gamma, const float* __restrict__ beta,
        float* __restrict__ num, float* __restrict__ den) {
    int tid = threadIdx.x;
    int c  = tid & 63;                       // channel == lane
    int wv = tid >> 6;
    // BN folded: z = relu(h*sc + sb)
    float inv = 1.0f / (float)N_NODES;
    float mu  = stats[c] * inv;
    float var = stats[HDIM + c] * inv - mu * mu;
    float sc  = rsqrtf(var + 1e-5f) * gamma[c];
    float sb  = beta[c] - mu * sc;
    float w[EDIM];
#pragma unroll
    for (int k = 0; k < EDIM; k++) w[k] = We[k * HDIM + c];
    float bc = be[c];
    float tval = *tptr;

    // this lane's own edge (position p in sorted order)
    int p = (blockIdx.x * 4 + wv) * 64 + c;      // grid sized so p < E always
    int d_own = dsts[p];
    int s_own = srcs[p];
    int e     = sorted[p];
    float a[EDIM];
    {
        const float4* ar = (const float4*)(ea + (size_t)e * EDIM);
        float4 a0 = ar[0], a1 = ar[1], a2 = ar[2], a3 = ar[3];
        a[0]=a0.x; a[1]=a0.y; a[2]=a0.z; a[3]=a0.w;
        a[4]=a1.x; a[5]=a1.y; a[6]=a1.z; a[7]=a1.w;
        a[8]=a2.x; a[9]=a2.y; a[10]=a2.z; a[11]=a2.w;
        a[12]=a3.x; a[13]=a3.y; a[14]=a3.z; a[15]=a3.w;
    }

    float nacc = 0.f, dacc = 0.f;
    int cur_d = __builtin_amdgcn_readlane(d_own, 0);
    for (int jj = 0; jj < 64; jj += 8) {
        // issue 8 h-row gathers ahead (independent vector loads)
        float hv[8];
#pragma unroll
        for (int u = 0; u < 8; u++) {
            int su = __builtin_amdgcn_readlane(s_own, jj + u);
            hv[u] = h[(size_t)su * HDIM + c];
        }
#pragma unroll
        for (int u = 0; u < 8; u++) {
            int du = __builtin_amdgcn_readlane(d_own, jj + u);
            if (du != cur_d) {               // wave-uniform scalar branch
                atomicAdd(&num[(size_t)cur_d * HDIM + c], nacc);
                atomicAdd(&den[(size_t)cur_d * HDIM + c], dacc);
                nacc = 0.f; dacc = 0.f;
                cur_d = du;
            }
            float acc = bc;
#pragma unroll
            for (int k = 0; k < EDIM; k++) {
                float ak = __uint_as_float(
                    __builtin_amdgcn_readlane(__float_as_uint(a[k]), jj + u));
                acc += ak * w[k];
            }
            float zv = fmaxf(hv[u] * sc + sb, 0.f);
            float m  = fmaxf(zv + acc, 0.f) + 1e-7f;
            float ex = __expf(m * tval);
            dacc += ex;
            nacc += ex * m;
        }
    }
    atomicAdd(&num[(size_t)cur_d * HDIM + c], nacc);
    atomicAdd(&den[(size_t)cur_d * HDIM + c], dacc);
}

// ---------------------------------------------------------------- MLP part 1
// Fused finalize: in = num/(den+eps) + relu(BN(h)); self-cleans num/den.
// Fused BN-stats epilogue for h1 (tile still in registers) -> statsB.
__global__ __launch_bounds__(256) void mlp1_kernel(
        float* __restrict__ num, float* __restrict__ den,
        const float* __restrict__ h, const float* __restrict__ stats,
        const float* __restrict__ gamma, const float* __restrict__ beta,
        const float* __restrict__ W1, const float* __restrict__ b1,
        float* __restrict__ h1, float* __restrict__ statsB, int N) {
    __shared__ float sW[HDIM * 128];         // 32 KB
    __shared__ float srow[32 * 65];          // +1 pad; reused for stats reduce
    int tid = threadIdx.x;
    for (int i = tid; i < HDIM * 128; i += 256) sW[i] = W1[i];
    int base = blockIdx.x * 32;
    {
        int cc = tid & 63;                   // constant across the i-loop (256%64==0)
        float inv = 1.0f / (float)N_NODES;
        float mu  = stats[cc] * inv;
        float var = stats[HDIM + cc] * inv - mu * mu;
        float rs  = rsqrtf(var + 1e-5f);
        float ga  = gamma[cc], bb = beta[cc];
        for (int i = tid; i < 32 * HDIM; i += 256) {
            int r = i >> 6;
            int node = base + r;
            float v = 0.f;
            if (node < N) {
                size_t idx = (size_t)node * HDIM + cc;
                float hv = h[idx];
                float z  = fmaxf((hv - mu) * rs * ga + bb, 0.f);
                float nu = num[idx], de = den[idx];
                num[idx] = 0.f; den[idx] = 0.f;   // ready for next layer
                v = nu / (de + 1e-16f) + z;
            }
            srow[r * 65 + cc] = v;
        }
    }
    __syncthreads();
    int tx = tid & 31;                       // outputs 4*tx .. 4*tx+3
    int ty = tid >> 5;                       // nodes ty*4 .. ty*4+3
    float acc[4][4];
    float b0 = b1[4 * tx], bb1 = b1[4 * tx + 1], b2v = b1[4 * tx + 2], b3 = b1[4 * tx + 3];
#pragma unroll
    for (int j = 0; j < 4; j++) { acc[j][0] = b0; acc[j][1] = bb1; acc[j][2] = b2v; acc[j][3] = b3; }
#pragma unroll 8
    for (int k = 0; k < HDIM; k++) {
        float4 wv = *(const float4*)&sW[k * 128 + 4 * tx];
        float r0 = srow[(ty * 4 + 0) * 65 + k];
        float r1 = srow[(ty * 4 + 1) * 65 + k];
        float r2 = srow[(ty * 4 + 2) * 65 + k];
        float r3 = srow[(ty * 4 + 3) * 65 + k];
        acc[0][0] += r0 * wv.x; acc[0][1] += r0 * wv.y; acc[0][2] += r0 * wv.z; acc[0][3] += r0 * wv.w;
        acc[1][0] += r1 * wv.x; acc[1][1] += r1 * wv.y; acc[1][2] += r1 * wv.z; acc[1][3] += r1 * wv.w;
        acc[2][0] += r2 * wv.x; acc[2][1] += r2 * wv.y; acc[2][2] += r2 * wv.z; acc[2][3] += r2 * wv.w;
        acc[3][0] += r3 * wv.x; acc[3][1] += r3 * wv.y; acc[3][2] += r3 * wv.z; acc[3][3] += r3 * wv.w;
    }
    float ps[4] = {0.f,0.f,0.f,0.f}, pq[4] = {0.f,0.f,0.f,0.f};
#pragma unroll
    for (int j = 0; j < 4; j++) {
        int node = base + ty * 4 + j;
        if (node < N) {
            *(float4*)&h1[(size_t)node * 128 + 4 * tx] =
                make_float4(acc[j][0], acc[j][1], acc[j][2], acc[j][3]);
#pragma unroll
            for (int q = 0; q < 4; q++) { ps[q] += acc[j][q]; pq[q] += acc[j][q] * acc[j][q]; }
        }
    }
    // ---- stats reduce (reuse srow: 2080 floats >= 2048) ----
    __syncthreads();                         // all srow reads done
    float* sredS = &srow[0];
    float* sredQ = &srow[1024];
    int sl = (tx * 8 + ty) * 4;
#pragma unroll
    for (int q = 0; q < 4; q++) { sredS[sl + q] = ps[q]; sredQ[sl + q] = pq[q]; }
    __syncthreads();
    if (tid < 128) {
        int txx = tid >> 2, q = tid & 3;
        float s2 = 0.f, q2 = 0.f;
#pragma unroll
        for (int t2 = 0; t2 < 8; t2++) {
            s2 += sredS[(txx * 8 + t2) * 4 + q];
            q2 += sredQ[(txx * 8 + t2) * 4 + q];
        }
        atomicAdd(&statsB[tid], s2);
        atomicAdd(&statsB[128 + tid], q2);
    }
}

// ---------------------------------------------------------------- MLP part 2
// h += relu(BN(h1)) @ W2 + b2; optional fused BN-stats of the NEW h -> statsNext
// (used for layer 0 only; layer 1's h feeds pooling, no BN).
__global__ __launch_bounds__(256) void mlp2_kernel(
        const float* __restrict__ h1, const float* __restrict__ stats,
        const float* __restrict__ mg, const float* __restrict__ mb,
        const float* __restrict__ W2, const float* __restrict__ b2,
        float* __restrict__ h, float* __restrict__ statsNext, int N) {
    __shared__ float sW[128 * HDIM];         // 32 KB
    __shared__ float sact[32 * 129];         // 16.5 KB; reused for stats reduce
    __shared__ float sbn[4 * 128];           // mu, rs, gamma, beta
    int tid = threadIdx.x;
    for (int i = tid; i < 128 * HDIM; i += 256) sW[i] = W2[i];
    if (tid < 128) {
        float inv = 1.0f / (float)N;
        float mu  = stats[tid] * inv;
        float var = stats[128 + tid] * inv - mu * mu;
        sbn[tid]       = mu;
        sbn[128 + tid] = rsqrtf(var + 1e-5f);
        sbn[256 + tid] = mg[tid];
        sbn[384 + tid] = mb[tid];
    }
    __syncthreads();
    int base = blockIdx.x * 32;
    for (int i = tid; i < 32 * 128; i += 256) {
        int r = i >> 7, o = i & 127;
        int node = base + r;
        float v = 0.f;
        if (node < N) {
            v = h1[(size_t)node * 128 + o];
            v = fmaxf((v - sbn[o]) * sbn[128 + o] * sbn[256 + o] + sbn[384 + o], 0.f);
        }
        sact[r * 129 + o] = v;
    }
    __syncthreads();
    int tx = tid & 15;                       // outputs 4*tx .. 4*tx+3
    int ty = tid >> 4;                       // nodes ty*2, ty*2+1
    float acc[2][4];
    float b0 = b2[4 * tx], bb1 = b2[4 * tx + 1], b2v = b2[4 * tx + 2], b3 = b2[4 * tx + 3];
    acc[0][0] = b0; acc[0][1] = bb1; acc[0][2] = b2v; acc[0][3] = b3;
    acc[1][0] = b0; acc[1][1] = bb1; acc[1][2] = b2v; acc[1][3] = b3;
#pragma unroll 8
    for (int k = 0; k < 128; k++) {
        float4 wv = *(const float4*)&sW[k * HDIM + 4 * tx];
        float r0 = sact[(ty * 2 + 0) * 129 + k];
        float r1 = sact[(ty * 2 + 1) * 129 + k];
        acc[0][0] += r0 * wv.x; acc[0][1] += r0 * wv.y; acc[0][2] += r0 * wv.z; acc[0][3] += r0 * wv.w;
        acc[1][0] += r1 * wv.x; acc[1][1] += r1 * wv.y; acc[1][2] += r1 * wv.z; acc[1][3] += r1 * wv.w;
    }
    float ps[4] = {0.f,0.f,0.f,0.f}, pq[4] = {0.f,0.f,0.f,0.f};
#pragma unroll
    for (int j = 0; j < 2; j++) {
        int node = base + ty * 2 + j;
        if (node < N) {
            float4* p = (float4*)&h[(size_t)node * HDIM + 4 * tx];
            float4 old = *p;
            float n0 = old.x + acc[j][0], n1 = old.y + acc[j][1];
            float n2 = old.z + acc[j][2], n3 = old.w + acc[j][3];
            *p = make_float4(n0, n1, n2, n3);
            ps[0] += n0; pq[0] += n0 * n0;
            ps[1] += n1; pq[1] += n1 * n1;
            ps[2] += n2; pq[2] += n2 * n2;
            ps[3] += n3; pq[3] += n3 * n3;
        }
    }
    if (statsNext) {                         // block-uniform branch
        __syncthreads();                     // all sact reads done
        float* sredS = &sact[0];
        float* sredQ = &sact[1024];
        int sl = (tx * 16 + ty) * 4;
#pragma unroll
        for (int q = 0; q < 4; q++) { sredS[sl + q] = ps[q]; sredQ[sl + q] = pq[q]; }
        __syncthreads();
        if (tid < 64) {
            int txx = tid >> 2, q = tid & 3;
            float s2 = 0.f, q2 = 0.f;
#pragma unroll
            for (int t2 = 0; t2 < 16; t2++) {
                s2 += sredS[(txx * 16 + t2) * 4 + q];
                q2 += sredQ[(txx * 16 + t2) * 4 + q];
            }
            atomicAdd(&statsNext[tid], s2);
            atomicAdd(&statsNext[HDIM + tid], q2);
        }
    }
}

// ---------------------------------------------------------------- pool + head
__global__ void pool_out_kernel(const float* __restrict__ h, const int* __restrict__ gstart,
                                const float* __restrict__ Wo, const float* __restrict__ bo,
                                float* __restrict__ out, int N) {
    __shared__ float sp[HDIM];
    __shared__ float red[256];
    __shared__ float sW[HDIM * COUT];
    int g = blockIdx.x;
    int tid = threadIdx.x;
    for (int i = tid; i < HDIM * COUT; i += 256) sW[i] = Wo[i];
    int beg = gstart[g], end = gstart[g + 1];
    int c = tid & 63, r0 = tid >> 6;
    float s = 0.f;
    for (int r = beg + r0; r < end; r += 4) s += h[(size_t)r * HDIM + c];
    red[tid] = s;
    __syncthreads();
    if (tid < HDIM) {
        s = red[tid] + red[tid + 64] + red[tid + 128] + red[tid + 192];
        float cnt = (float)(end - beg);
        float pooled = s / fmaxf(cnt, 1.0f);
        sp[tid] = fmaxf(pooled, 0.0f);
    }
    __syncthreads();
    if (tid < COUT) {
        float acc = bo[tid];
#pragma unroll
        for (int k = 0; k < HDIM; k++) acc += sp[k] * sW[k * COUT + tid];
        out[g * COUT + tid] = acc;
    }
}

// ================================================================ launch
extern "C" void kernel_launch(void* const* d_in, const int* in_sizes, int n_in,
                              void* d_out, int out_size, void* d_ws, size_t ws_size,
                              hipStream_t stream) {
    (void)in_sizes; (void)n_in; (void)out_size; (void)ws_size;
    const float* x          = (const float*)d_in[0];
    const int*   eidx       = (const int*)  d_in[1];
    const float* eattr      = (const float*)d_in[2];
    const int*   batch      = (const int*)  d_in[3];
    const float* lin_in_w   = (const float*)d_in[4];
    const float* lin_in_b   = (const float*)d_in[5];
    const float* norm_gamma = (const float*)d_in[6];
    const float* norm_beta  = (const float*)d_in[7];
    const float* edge_w     = (const float*)d_in[8];
    const float* edge_b     = (const float*)d_in[9];
    const float* tparam     = (const float*)d_in[10];
    const float* mlp_w1     = (const float*)d_in[11];
    const float* mlp_b1     = (const float*)d_in[12];
    const float* mlp_gamma  = (const float*)d_in[13];
    const float* mlp_beta   = (const float*)d_in[14];
    const float* mlp_w2     = (const float*)d_in[15];
    const float* mlp_b2     = (const float*)d_in[16];
    const float* lin_out_w  = (const float*)d_in[17];
    const float* lin_out_b  = (const float*)d_in[18];
    float* out = (float*)d_out;

    const int* src = eidx;                   // edge_index[0]
    const int* dst = eidx + N_EDGES;         // edge_index[1]

    char* ws = (char*)d_ws;
    size_t off = 0;
    auto alloc = [&](size_t bytes) -> char* {
        char* p = ws + off;
        off = (off + bytes + 255) & ~(size_t)255;
        return p;
    };
    // zero-init region first (one memset covers histogram + all BN stats)
    int*   cnt     = (int*)  alloc((size_t)N_NODES * 4);
    float* statsA0 = (float*)alloc(128 * 4);
    float* statsB0 = (float*)alloc(256 * 4);
    float* statsA1 = (float*)alloc(128 * 4);
    float* statsB1 = (float*)alloc(256 * 4);
    size_t zero_bytes = off;
    int*   offsets = (int*)  alloc((size_t)(N_NODES + 1) * 4);
    int*   cursor  = (int*)  alloc((size_t)N_NODES * 4);
    int*   sorted  = (int*)  alloc((size_t)N_EDGES * 4);
    int*   dsts    = (int*)  alloc((size_t)N_EDGES * 4);
    int*   srcs    = (int*)  alloc((size_t)N_EDGES * 4);
    int*   gstart  = (int*)  alloc((size_t)(NGRAPH + 1) * 4);
    float* h       = (float*)alloc((size_t)N_NODES * HDIM * 4);
    float* num     = (float*)alloc((size_t)N_NODES * HDIM * 4);
    float* den     = (float*)alloc((size_t)N_NODES * HDIM * 4);   // contiguous after num
    float* h1      = (float*)alloc((size_t)N_NODES * 2 * HDIM * 4);

    hipMemsetAsync(d_ws, 0, zero_bytes, stream);
    // num+den zeroed once; mlp1 self-cleans them for the next layer
    hipMemsetAsync(num, 0, (size_t)N_NODES * HDIM * 4 * 2, stream);

    const int NB = (N_NODES + 255) / 256;    // 196 blocks
    hist_kernel    <<<(N_EDGES + 255) / 256, 256, 0, stream>>>(dst, cnt, N_EDGES);
    scan_all_kernel<<<1, 1024, 0, stream>>>(cnt, offsets, cursor, N_NODES);
    scatter_kernel <<<(N_EDGES + 255) / 256, 256, 0, stream>>>(dst, src, cursor, sorted, dsts, srcs, N_EDGES);
    gstart_kernel  <<<NB, 256, 0, stream>>>(batch, gstart, N_NODES, NGRAPH);
    // lin_in fuses statsA0 (grid-stride, 256 blocks -> low atomic contention)
    lin_in_kernel  <<<256, 256, 0, stream>>>(x, lin_in_w, lin_in_b, h, statsA0, N_NODES);

    const int AGG_BLOCKS = N_EDGES / 256;    // 3125, exact (4 waves x 64 edges)

    float* statsA[2] = { statsA0, statsA1 };
    float* statsB[2] = { statsB0, statsB1 };
    for (int l = 0; l < 2; l++) {
        edge_agg_kernel<<<AGG_BLOCKS, 256, 0, stream>>>(
            h, eattr, sorted, dsts, srcs,
            edge_w + (size_t)l * EDIM * HDIM, edge_b + l * HDIM,
            tparam + l, statsA[l], norm_gamma + l * HDIM, norm_beta + l * HDIM,
            num, den);
        // mlp1 fuses statsB[l] epilogue (h1 tile still in registers)
        mlp1_kernel<<<(N_NODES + 31) / 32, 256, 0, stream>>>(
            num, den, h, statsA[l], norm_gamma + l * HDIM, norm_beta + l * HDIM,
            mlp_w1 + (size_t)l * HDIM * 2 * HDIM, mlp_b1 + l * 2 * HDIM, h1,
            statsB[l], N_NODES);
        // mlp2 fuses statsA1 epilogue on layer 0 (layer 1 h is not BN'd)
        mlp2_kernel<<<(N_NODES + 31) / 32, 256, 0, stream>>>(
            h1, statsB[l], mlp_gamma + l * 2 * HDIM, mlp_beta + l * 2 * HDIM,
            mlp_w2 + (size_t)l * 2 * HDIM * HDIM, mlp_b2 + l * HDIM, h,
            (l == 0) ? statsA1 : (float*)nullptr, N_NODES);
    }
    pool_out_kernel<<<NGRAPH, 256, 0, stream>>>(h, gstart, lin_out_w, lin_out_b, out, N_NODES);
}

// Round 7
// 654.353 us; speedup vs baseline: 1.2483x; 1.2483x over previous
//
#include <hip/hip_runtime.h>

#define N_NODES 50000
#define N_EDGES 800000
#define F_INP   32
#define HDIM    64
#define EDIM    16
#define COUT    40
#define NGRAPH  64
#define LDS_STRIDE 18   // floats per staged attr row: 16 + 2 pad (keeps b64 align, spreads banks)

// ---------------------------------------------------------------- sort by dst
__global__ void hist_kernel(const int* __restrict__ dst, int* __restrict__ cnt, int E) {
    int e = blockIdx.x * 256 + threadIdx.x;
    if (e < E) atomicAdd(&cnt[dst[e]], 1);
}

// 3-stage scan: block partial sums -> 1-block scan of sums -> apply
__global__ void scan_part_kernel(const int* __restrict__ cnt, int* __restrict__ bsum, int n) {
    __shared__ int red[256];
    int tid = threadIdx.x;
    int idx = blockIdx.x * 256 + tid;
    red[tid] = (idx < n) ? cnt[idx] : 0;
    __syncthreads();
    for (int off = 128; off > 0; off >>= 1) {
        if (tid < off) red[tid] += red[tid + off];
        __syncthreads();
    }
    if (tid == 0) bsum[blockIdx.x] = red[0];
}

__global__ void scan_top_kernel(int* __restrict__ bsum, int nb) {
    __shared__ int tmp[256];
    int tid = threadIdx.x;
    int v = (tid < nb) ? bsum[tid] : 0;
    tmp[tid] = v;
    __syncthreads();
    for (int off = 1; off < 256; off <<= 1) {
        int x = (tid >= off) ? tmp[tid - off] : 0;
        __syncthreads();
        tmp[tid] += x;
        __syncthreads();
    }
    if (tid < nb) bsum[tid] = tmp[tid] - v;   // exclusive
}

__global__ void scan_apply_kernel(const int* __restrict__ cnt, const int* __restrict__ bsum,
                                  int* __restrict__ offsets, int* __restrict__ cursor, int n) {
    __shared__ int tmp[256];
    int tid = threadIdx.x;
    int idx = blockIdx.x * 256 + tid;
    int v = (idx < n) ? cnt[idx] : 0;
    tmp[tid] = v;
    __syncthreads();
    for (int off = 1; off < 256; off <<= 1) {
        int x = (tid >= off) ? tmp[tid - off] : 0;
        __syncthreads();
        tmp[tid] += x;
        __syncthreads();
    }
    int excl = tmp[tid] - v + bsum[blockIdx.x];
    if (idx < n) { offsets[idx] = excl; cursor[idx] = excl; }
    if (idx == n - 1) offsets[n] = excl + v;
}

// materialize per-sorted-position edge id, dst, and src
__global__ void scatter_kernel(const int* __restrict__ dst, const int* __restrict__ src,
                               int* __restrict__ cursor, int* __restrict__ sorted,
                               int* __restrict__ dsts, int* __restrict__ srcs, int E) {
    int e = blockIdx.x * 256 + threadIdx.x;
    if (e < E) {
        int d = dst[e];
        int p = atomicAdd(&cursor[d], 1);
        sorted[p] = e;
        dsts[p]   = d;
        srcs[p]   = src[e];
    }
}

// batch is sorted ascending; find graph start offsets
__global__ void gstart_kernel(const int* __restrict__ batch, int* __restrict__ gstart,
                              int N, int G) {
    int n = blockIdx.x * 256 + threadIdx.x;
    if (n >= N) return;
    int g  = batch[n];
    int gp = (n == 0) ? -1 : batch[n - 1];
    for (int gg = gp + 1; gg <= g; gg++) gstart[gg] = n;
    if (n == N - 1) {
        for (int gg = g + 1; gg <= G; gg++) gstart[gg] = N;
    }
}

// ---------------------------------------------------------------- input linear
__global__ void lin_in_kernel(const float* __restrict__ x, const float* __restrict__ W,
                              const float* __restrict__ b, float* __restrict__ h, int N) {
    int tid = threadIdx.x;
    int c = tid & 63;
    float w[F_INP];
#pragma unroll
    for (int k = 0; k < F_INP; k++) w[k] = W[k * HDIM + c];
    int node = blockIdx.x * 4 + (tid >> 6);
    if (node >= N) return;
    const float4* xr = (const float4*)(x + (size_t)node * F_INP);
    float acc = b[c];
#pragma unroll
    for (int k4 = 0; k4 < F_INP / 4; k4++) {
        float4 xv = xr[k4];
        acc += xv.x * w[k4 * 4 + 0] + xv.y * w[k4 * 4 + 1]
             + xv.z * w[k4 * 4 + 2] + xv.w * w[k4 * 4 + 3];
    }
    h[(size_t)node * HDIM + c] = acc;
}

// ---------------------------------------------------------------- BN stats
template <int C>
__global__ void bn_stats_kernel(const float* __restrict__ x, float* __restrict__ stats, int N) {
    const int RPB = 256 / C;
    int tid = threadIdx.x;
    int c = tid % C;
    int row0 = blockIdx.x * RPB + tid / C;
    int stride = gridDim.x * RPB;
    float s = 0.f, ss = 0.f;
    for (int r = row0; r < N; r += stride) {
        float v = x[(size_t)r * C + c];
        s += v; ss += v * v;
    }
    __shared__ float ls[256], lss[256];
    ls[tid] = s; lss[tid] = ss;
    __syncthreads();
    if (tid < C) {
        for (int k = 1; k < RPB; k++) { s += ls[tid + k * C]; ss += lss[tid + k * C]; }
        atomicAdd(&stats[c], s);
        atomicAdd(&stats[C + c], ss);
    }
}

// ---------------------------------------------------------------- edge-parallel aggregation
// One wave per 64 contiguous dst-sorted positions; ONE EDGE PER LANE.
// Round-6 lesson: kernel is VALU-ISSUE-bound (80% busy); the 16 v_readlane
// attr broadcasts per edge were ~35% of the issue stream. This version stages
// each wave's 64 attr rows in LDS once (16 ds_write_b32, conflict-lite,
// amortized 0.25 inst/edge) and broadcasts via 8 same-address ds_read_b64
// per edge — moving the broadcast from the VALU pipe to the idle DS pipe.
// exp folded: exp(m*t) = exp2(m * t*log2e) saves one v_mul per edge.
__global__ __launch_bounds__(256) void edge_agg_kernel(
        const float* __restrict__ h, const float* __restrict__ ea,
        const int* __restrict__ sorted, const int* __restrict__ dsts,
        const int* __restrict__ srcs,
        const float* __restrict__ We, const float* __restrict__ be,
        const float* __restrict__ tptr, const float* __restrict__ stats,
        const float* __restrict__ gamma, const float* __restrict__ beta,
        float* __restrict__ num, float* __restrict__ den) {
    __shared__ float sA[4 * 64 * LDS_STRIDE];    // 4 waves x 64 edges x 18 f = 18 KB
    int tid = threadIdx.x;
    int c  = tid & 63;                       // channel == lane
    int wv = tid >> 6;
    // BN folded: z = relu(h*sc + sb)
    float inv = 1.0f / (float)N_NODES;
    float mu  = stats[c] * inv;
    float var = stats[HDIM + c] * inv - mu * mu;
    float sc  = rsqrtf(var + 1e-5f) * gamma[c];
    float sb  = beta[c] - mu * sc;
    float w[EDIM];
#pragma unroll
    for (int k = 0; k < EDIM; k++) w[k] = We[k * HDIM + c];
    float bc = be[c];
    float tl2 = (*tptr) * 1.4426950408889634f;   // t * log2(e)

    // this lane's own edge (position p in sorted order)
    int p = (blockIdx.x * 4 + wv) * 64 + c;      // grid sized so p < E always
    int d_own = dsts[p];
    int s_own = srcs[p];
    int e     = sorted[p];
    // stage own attr row to LDS
    float* myrow = &sA[(wv * 64 + c) * LDS_STRIDE];
    {
        const float4* ar = (const float4*)(ea + (size_t)e * EDIM);
        float4 a0 = ar[0], a1 = ar[1], a2 = ar[2], a3 = ar[3];
        myrow[0]=a0.x;  myrow[1]=a0.y;  myrow[2]=a0.z;  myrow[3]=a0.w;
        myrow[4]=a1.x;  myrow[5]=a1.y;  myrow[6]=a1.z;  myrow[7]=a1.w;
        myrow[8]=a2.x;  myrow[9]=a2.y;  myrow[10]=a2.z; myrow[11]=a2.w;
        myrow[12]=a3.x; myrow[13]=a3.y; myrow[14]=a3.z; myrow[15]=a3.w;
    }
    __syncthreads();                         // staging visible (per-wave use only)

    const float* wrow = &sA[(size_t)wv * 64 * LDS_STRIDE];
    float nacc = 0.f, dacc = 0.f;
    int cur_d = __builtin_amdgcn_readlane(d_own, 0);
    for (int jj = 0; jj < 64; jj += 8) {
        // issue 8 h-row gathers ahead (independent vector loads)
        float hv[8];
#pragma unroll
        for (int u = 0; u < 8; u++) {
            int su = __builtin_amdgcn_readlane(s_own, jj + u);
            hv[u] = h[(size_t)su * HDIM + c];
        }
#pragma unroll
        for (int u = 0; u < 8; u++) {
            int du = __builtin_amdgcn_readlane(d_own, jj + u);
            if (du != cur_d) {               // wave-uniform scalar branch
                atomicAdd(&num[(size_t)cur_d * HDIM + c], nacc);
                atomicAdd(&den[(size_t)cur_d * HDIM + c], dacc);
                nacc = 0.f; dacc = 0.f;
                cur_d = du;
            }
            // broadcast attr row via same-address ds_read_b64 (DS pipe, no conflict)
            const float2* arow = (const float2*)&wrow[(jj + u) * LDS_STRIDE];
            float acc = bc;
#pragma unroll
            for (int k2 = 0; k2 < 8; k2++) {
                float2 av = arow[k2];
                acc += av.x * w[2 * k2] + av.y * w[2 * k2 + 1];
            }
            float zv = fmaxf(hv[u] * sc + sb, 0.f);
            float m  = fmaxf(zv + acc, 0.f) + 1e-7f;
            float ex = exp2f(m * tl2);
            dacc += ex;
            nacc += ex * m;
        }
    }
    atomicAdd(&num[(size_t)cur_d * HDIM + c], nacc);
    atomicAdd(&den[(size_t)cur_d * HDIM + c], dacc);
}

// ---------------------------------------------------------------- MLP part 1
// Fused finalize: in = num/(den+eps) + relu(BN(h)); also self-cleans num/den
// to zero for the next layer (each idx touched exactly once).
__global__ __launch_bounds__(256) void mlp1_kernel(
        float* __restrict__ num, float* __restrict__ den,
        const float* __restrict__ h, const float* __restrict__ stats,
        const float* __restrict__ gamma, const float* __restrict__ beta,
        const float* __restrict__ W1, const float* __restrict__ b1,
        float* __restrict__ h1, int N) {
    __shared__ float sW[HDIM * 128];         // 32 KB
    __shared__ float srow[32 * 65];          // +1 pad breaks bank stride
    int tid = threadIdx.x;
    for (int i = tid; i < HDIM * 128; i += 256) sW[i] = W1[i];
    int base = blockIdx.x * 32;
    {
        int cc = tid & 63;                   // constant across the i-loop (256%64==0)
        float inv = 1.0f / (float)N_NODES;
        float mu  = stats[cc] * inv;
        float var = stats[HDIM + cc] * inv - mu * mu;
        float rs  = rsqrtf(var + 1e-5f);
        float ga  = gamma[cc], bb = beta[cc];
        for (int i = tid; i < 32 * HDIM; i += 256) {
            int r = i >> 6;
            int node = base + r;
            float v = 0.f;
            if (node < N) {
                size_t idx = (size_t)node * HDIM + cc;
                float hv = h[idx];
                float z  = fmaxf((hv - mu) * rs * ga + bb, 0.f);
                float nu = num[idx], de = den[idx];
                num[idx] = 0.f; den[idx] = 0.f;   // ready for next layer
                v = nu / (de + 1e-16f) + z;
            }
            srow[r * 65 + cc] = v;
        }
    }
    __syncthreads();
    int tx = tid & 31;                       // outputs 4*tx .. 4*tx+3
    int ty = tid >> 5;                       // nodes ty*4 .. ty*4+3
    float acc[4][4];
    float b0 = b1[4 * tx], bb1 = b1[4 * tx + 1], b2v = b1[4 * tx + 2], b3 = b1[4 * tx + 3];
#pragma unroll
    for (int j = 0; j < 4; j++) { acc[j][0] = b0; acc[j][1] = bb1; acc[j][2] = b2v; acc[j][3] = b3; }
#pragma unroll 8
    for (int k = 0; k < HDIM; k++) {
        float4 wv = *(const float4*)&sW[k * 128 + 4 * tx];
        float r0 = srow[(ty * 4 + 0) * 65 + k];
        float r1 = srow[(ty * 4 + 1) * 65 + k];
        float r2 = srow[(ty * 4 + 2) * 65 + k];
        float r3 = srow[(ty * 4 + 3) * 65 + k];
        acc[0][0] += r0 * wv.x; acc[0][1] += r0 * wv.y; acc[0][2] += r0 * wv.z; acc[0][3] += r0 * wv.w;
        acc[1][0] += r1 * wv.x; acc[1][1] += r1 * wv.y; acc[1][2] += r1 * wv.z; acc[1][3] += r1 * wv.w;
        acc[2][0] += r2 * wv.x; acc[2][1] += r2 * wv.y; acc[2][2] += r2 * wv.z; acc[2][3] += r2 * wv.w;
        acc[3][0] += r3 * wv.x; acc[3][1] += r3 * wv.y; acc[3][2] += r3 * wv.z; acc[3][3] += r3 * wv.w;
    }
#pragma unroll
    for (int j = 0; j < 4; j++) {
        int node = base + ty * 4 + j;
        if (node < N)
            *(float4*)&h1[(size_t)node * 128 + 4 * tx] =
                make_float4(acc[j][0], acc[j][1], acc[j][2], acc[j][3]);
    }
}

// ---------------------------------------------------------------- MLP part 2
__global__ __launch_bounds__(256) void mlp2_kernel(
        const float* __restrict__ h1, const float* __restrict__ stats,
        const float* __restrict__ mg, const float* __restrict__ mb,
        const float* __restrict__ W2, const float* __restrict__ b2,
        float* __restrict__ h, int N) {
    __shared__ float sW[128 * HDIM];         // 32 KB
    __shared__ float sact[32 * 129];         // 16.5 KB, +1 pad
    __shared__ float sbn[4 * 128];           // mu, rs, gamma, beta
    int tid = threadIdx.x;
    for (int i = tid; i < 128 * HDIM; i += 256) sW[i] = W2[i];
    if (tid < 128) {
        float inv = 1.0f / (float)N;
        float mu  = stats[tid] * inv;
        float var = stats[128 + tid] * inv - mu * mu;
        sbn[tid]       = mu;
        sbn[128 + tid] = rsqrtf(var + 1e-5f);
        sbn[256 + tid] = mg[tid];
        sbn[384 + tid] = mb[tid];
    }
    __syncthreads();
    int base = blockIdx.x * 32;
    for (int i = tid; i < 32 * 128; i += 256) {
        int r = i >> 7, o = i & 127;
        int node = base + r;
        float v = 0.f;
        if (node < N) {
            v = h1[(size_t)node * 128 + o];
            v = fmaxf((v - sbn[o]) * sbn[128 + o] * sbn[256 + o] + sbn[384 + o], 0.f);
        }
        sact[r * 129 + o] = v;
    }
    __syncthreads();
    int tx = tid & 15;                       // outputs 4*tx .. 4*tx+3
    int ty = tid >> 4;                       // nodes ty*2, ty*2+1
    float acc[2][4];
    float b0 = b2[4 * tx], bb1 = b2[4 * tx + 1], b2v = b2[4 * tx + 2], b3 = b2[4 * tx + 3];
    acc[0][0] = b0; acc[0][1] = bb1; acc[0][2] = b2v; acc[0][3] = b3;
    acc[1][0] = b0; acc[1][1] = bb1; acc[1][2] = b2v; acc[1][3] = b3;
#pragma unroll 8
    for (int k = 0; k < 128; k++) {
        float4 wv = *(const float4*)&sW[k * HDIM + 4 * tx];
        float r0 = sact[(ty * 2 + 0) * 129 + k];
        float r1 = sact[(ty * 2 + 1) * 129 + k];
        acc[0][0] += r0 * wv.x; acc[0][1] += r0 * wv.y; acc[0][2] += r0 * wv.z; acc[0][3] += r0 * wv.w;
        acc[1][0] += r1 * wv.x; acc[1][1] += r1 * wv.y; acc[1][2] += r1 * wv.z; acc[1][3] += r1 * wv.w;
    }
#pragma unroll
    for (int j = 0; j < 2; j++) {
        int node = base + ty * 2 + j;
        if (node < N) {
            float4* p = (float4*)&h[(size_t)node * HDIM + 4 * tx];
            float4 old = *p;
            *p = make_float4(old.x + acc[j][0], old.y + acc[j][1],
                             old.z + acc[j][2], old.w + acc[j][3]);
        }
    }
}

// ---------------------------------------------------------------- pool + head
__global__ void pool_out_kernel(const float* __restrict__ h, const int* __restrict__ gstart,
                                const float* __restrict__ Wo, const float* __restrict__ bo,
                                float* __restrict__ out, int N) {
    __shared__ float sp[HDIM];
    __shared__ float red[256];
    __shared__ float sW[HDIM * COUT];
    int g = blockIdx.x;
    int tid = threadIdx.x;
    for (int i = tid; i < HDIM * COUT; i += 256) sW[i] = Wo[i];
    int beg = gstart[g], end = gstart[g + 1];
    int c = tid & 63, r0 = tid >> 6;
    float s = 0.f;
    for (int r = beg + r0; r < end; r += 4) s += h[(size_t)r * HDIM + c];
    red[tid] = s;
    __syncthreads();
    if (tid < HDIM) {
        s = red[tid] + red[tid + 64] + red[tid + 128] + red[tid + 192];
        float cnt = (float)(end - beg);
        float pooled = s / fmaxf(cnt, 1.0f);
        sp[tid] = fmaxf(pooled, 0.0f);
    }
    __syncthreads();
    if (tid < COUT) {
        float acc = bo[tid];
#pragma unroll
        for (int k = 0; k < HDIM; k++) acc += sp[k] * sW[k * COUT + tid];
        out[g * COUT + tid] = acc;
    }
}

// ================================================================ launch
extern "C" void kernel_launch(void* const* d_in, const int* in_sizes, int n_in,
                              void* d_out, int out_size, void* d_ws, size_t ws_size,
                              hipStream_t stream) {
    (void)in_sizes; (void)n_in; (void)out_size; (void)ws_size;
    const float* x          = (const float*)d_in[0];
    const int*   eidx       = (const int*)  d_in[1];
    const float* eattr      = (const float*)d_in[2];
    const int*   batch      = (const int*)  d_in[3];
    const float* lin_in_w   = (const float*)d_in[4];
    const float* lin_in_b   = (const float*)d_in[5];
    const float* norm_gamma = (const float*)d_in[6];
    const float* norm_beta  = (const float*)d_in[7];
    const float* edge_w     = (const float*)d_in[8];
    const float* edge_b     = (const float*)d_in[9];
    const float* tparam     = (const float*)d_in[10];
    const float* mlp_w1     = (const float*)d_in[11];
    const float* mlp_b1     = (const float*)d_in[12];
    const float* mlp_gamma  = (const float*)d_in[13];
    const float* mlp_beta   = (const float*)d_in[14];
    const float* mlp_w2     = (const float*)d_in[15];
    const float* mlp_b2     = (const float*)d_in[16];
    const float* lin_out_w  = (const float*)d_in[17];
    const float* lin_out_b  = (const float*)d_in[18];
    float* out = (float*)d_out;

    const int* src = eidx;                   // edge_index[0]
    const int* dst = eidx + N_EDGES;         // edge_index[1]

    char* ws = (char*)d_ws;
    size_t off = 0;
    auto alloc = [&](size_t bytes) -> char* {
        char* p = ws + off;
        off = (off + bytes + 255) & ~(size_t)255;
        return p;
    };
    // zero-init region first (one memset covers histogram + all BN stats)
    int*   cnt     = (int*)  alloc((size_t)N_NODES * 4);
    float* statsA0 = (float*)alloc(128 * 4);
    float* statsB0 = (float*)alloc(256 * 4);
    float* statsA1 = (float*)alloc(128 * 4);
    float* statsB1 = (float*)alloc(256 * 4);
    size_t zero_bytes = off;
    int*   bsum    = (int*)  alloc(256 * 4);
    int*   offsets = (int*)  alloc((size_t)(N_NODES + 1) * 4);
    int*   cursor  = (int*)  alloc((size_t)N_NODES * 4);
    int*   sorted  = (int*)  alloc((size_t)N_EDGES * 4);
    int*   dsts    = (int*)  alloc((size_t)N_EDGES * 4);
    int*   srcs    = (int*)  alloc((size_t)N_EDGES * 4);
    int*   gstart  = (int*)  alloc((size_t)(NGRAPH + 1) * 4);
    float* h       = (float*)alloc((size_t)N_NODES * HDIM * 4);
    float* num     = (float*)alloc((size_t)N_NODES * HDIM * 4);
    float* den     = (float*)alloc((size_t)N_NODES * HDIM * 4);   // contiguous after num
    float* h1      = (float*)alloc((size_t)N_NODES * 2 * HDIM * 4);

    hipMemsetAsync(d_ws, 0, zero_bytes, stream);
    // num+den zeroed once; mlp1 self-cleans them for the next layer
    hipMemsetAsync(num, 0, (size_t)N_NODES * HDIM * 4 * 2, stream);

    const int NB = (N_NODES + 255) / 256;    // 196 blocks
    hist_kernel      <<<(N_EDGES + 255) / 256, 256, 0, stream>>>(dst, cnt, N_EDGES);
    scan_part_kernel <<<NB, 256, 0, stream>>>(cnt, bsum, N_NODES);
    scan_top_kernel  <<<1, 256, 0, stream>>>(bsum, NB);
    scan_apply_kernel<<<NB, 256, 0, stream>>>(cnt, bsum, offsets, cursor, N_NODES);
    scatter_kernel   <<<(N_EDGES + 255) / 256, 256, 0, stream>>>(dst, src, cursor, sorted, dsts, srcs, N_EDGES);
    gstart_kernel    <<<NB, 256, 0, stream>>>(batch, gstart, N_NODES, NGRAPH);
    lin_in_kernel    <<<(N_NODES + 3) / 4, 256, 0, stream>>>(x, lin_in_w, lin_in_b, h, N_NODES);

    const int AGG_BLOCKS = N_EDGES / 256;    // 3125, exact (4 waves x 64 edges)

    float* statsA[2] = { statsA0, statsA1 };
    float* statsB[2] = { statsB0, statsB1 };
    for (int l = 0; l < 2; l++) {
        bn_stats_kernel<64><<<256, 256, 0, stream>>>(h, statsA[l], N_NODES);
        edge_agg_kernel<<<AGG_BLOCKS, 256, 0, stream>>>(
            h, eattr, sorted, dsts, srcs,
            edge_w + (size_t)l * EDIM * HDIM, edge_b + l * HDIM,
            tparam + l, statsA[l], norm_gamma + l * HDIM, norm_beta + l * HDIM,
            num, den);
        mlp1_kernel<<<(N_NODES + 31) / 32, 256, 0, stream>>>(
            num, den, h, statsA[l], norm_gamma + l * HDIM, norm_beta + l * HDIM,
            mlp_w1 + (size_t)l * HDIM * 2 * HDIM, mlp_b1 + l * 2 * HDIM, h1, N_NODES);
        bn_stats_kernel<128><<<256, 256, 0, stream>>>(h1, statsB[l], N_NODES);
        mlp2_kernel<<<(N_NODES + 31) / 32, 256, 0, stream>>>(
            h1, statsB[l], mlp_gamma + l * 2 * HDIM, mlp_beta + l * 2 * HDIM,
            mlp_w2 + (size_t)l * 2 * HDIM * HDIM, mlp_b2 + l * HDIM, h, N_NODES);
    }
    pool_out_kernel<<<NGRAPH, 256, 0, stream>>>(h, gstart, lin_out_w, lin_out_b, out, N_NODES);
}

// Round 8
// 631.817 us; speedup vs baseline: 1.2928x; 1.0357x over previous
//
#include <hip/hip_runtime.h>

#define N_NODES 50000
#define N_EDGES 800000
#define F_INP   32
#define HDIM    64
#define EDIM    16
#define COUT    40
#define NGRAPH  64
#define LDS_STRIDE 18   // floats per staged attr row: 16 + 2 pad (keeps b64 align, spreads banks)

typedef float v2f __attribute__((ext_vector_type(2)));

// ---------------------------------------------------------------- sort by dst
__global__ void hist_kernel(const int* __restrict__ dst, int* __restrict__ cnt, int E) {
    int e = blockIdx.x * 256 + threadIdx.x;
    if (e < E) atomicAdd(&cnt[dst[e]], 1);
}

// 3-stage scan: block partial sums -> 1-block scan of sums -> apply
__global__ void scan_part_kernel(const int* __restrict__ cnt, int* __restrict__ bsum, int n) {
    __shared__ int red[256];
    int tid = threadIdx.x;
    int idx = blockIdx.x * 256 + tid;
    red[tid] = (idx < n) ? cnt[idx] : 0;
    __syncthreads();
    for (int off = 128; off > 0; off >>= 1) {
        if (tid < off) red[tid] += red[tid + off];
        __syncthreads();
    }
    if (tid == 0) bsum[blockIdx.x] = red[0];
}

__global__ void scan_top_kernel(int* __restrict__ bsum, int nb) {
    __shared__ int tmp[256];
    int tid = threadIdx.x;
    int v = (tid < nb) ? bsum[tid] : 0;
    tmp[tid] = v;
    __syncthreads();
    for (int off = 1; off < 256; off <<= 1) {
        int x = (tid >= off) ? tmp[tid - off] : 0;
        __syncthreads();
        tmp[tid] += x;
        __syncthreads();
    }
    if (tid < nb) bsum[tid] = tmp[tid] - v;   // exclusive
}

__global__ void scan_apply_kernel(const int* __restrict__ cnt, const int* __restrict__ bsum,
                                  int* __restrict__ offsets, int* __restrict__ cursor, int n) {
    __shared__ int tmp[256];
    int tid = threadIdx.x;
    int idx = blockIdx.x * 256 + tid;
    int v = (idx < n) ? cnt[idx] : 0;
    tmp[tid] = v;
    __syncthreads();
    for (int off = 1; off < 256; off <<= 1) {
        int x = (tid >= off) ? tmp[tid - off] : 0;
        __syncthreads();
        tmp[tid] += x;
        __syncthreads();
    }
    int excl = tmp[tid] - v + bsum[blockIdx.x];
    if (idx < n) { offsets[idx] = excl; cursor[idx] = excl; }
    if (idx == n - 1) offsets[n] = excl + v;
}

// scatter packed: one int4 (dst, src, edge_id, 0) per sorted position.
// One random 16B write (1 cache line) per edge instead of three 4B writes
// to three separate arrays (3 lines) — cuts scatter's random-write traffic ~3x.
__global__ void scatter_kernel(const int* __restrict__ dst, const int* __restrict__ src,
                               int* __restrict__ cursor, int4* __restrict__ edge4, int E) {
    int e = blockIdx.x * 256 + threadIdx.x;
    if (e < E) {
        int d = dst[e];
        int p = atomicAdd(&cursor[d], 1);
        edge4[p] = make_int4(d, src[e], e, 0);
    }
}

// batch is sorted ascending; find graph start offsets
__global__ void gstart_kernel(const int* __restrict__ batch, int* __restrict__ gstart,
                              int N, int G) {
    int n = blockIdx.x * 256 + threadIdx.x;
    if (n >= N) return;
    int g  = batch[n];
    int gp = (n == 0) ? -1 : batch[n - 1];
    for (int gg = gp + 1; gg <= g; gg++) gstart[gg] = n;
    if (n == N - 1) {
        for (int gg = g + 1; gg <= G; gg++) gstart[gg] = N;
    }
}

// ---------------------------------------------------------------- input linear
__global__ void lin_in_kernel(const float* __restrict__ x, const float* __restrict__ W,
                              const float* __restrict__ b, float* __restrict__ h, int N) {
    int tid = threadIdx.x;
    int c = tid & 63;
    float w[F_INP];
#pragma unroll
    for (int k = 0; k < F_INP; k++) w[k] = W[k * HDIM + c];
    int node = blockIdx.x * 4 + (tid >> 6);
    if (node >= N) return;
    const float4* xr = (const float4*)(x + (size_t)node * F_INP);
    float acc = b[c];
#pragma unroll
    for (int k4 = 0; k4 < F_INP / 4; k4++) {
        float4 xv = xr[k4];
        acc += xv.x * w[k4 * 4 + 0] + xv.y * w[k4 * 4 + 1]
             + xv.z * w[k4 * 4 + 2] + xv.w * w[k4 * 4 + 3];
    }
    h[(size_t)node * HDIM + c] = acc;
}

// ---------------------------------------------------------------- BN stats
template <int C>
__global__ void bn_stats_kernel(const float* __restrict__ x, float* __restrict__ stats, int N) {
    const int RPB = 256 / C;
    int tid = threadIdx.x;
    int c = tid % C;
    int row0 = blockIdx.x * RPB + tid / C;
    int stride = gridDim.x * RPB;
    float s = 0.f, ss = 0.f;
    for (int r = row0; r < N; r += stride) {
        float v = x[(size_t)r * C + c];
        s += v; ss += v * v;
    }
    __shared__ float ls[256], lss[256];
    ls[tid] = s; lss[tid] = ss;
    __syncthreads();
    if (tid < C) {
        for (int k = 1; k < RPB; k++) { s += ls[tid + k * C]; ss += lss[tid + k * C]; }
        atomicAdd(&stats[c], s);
        atomicAdd(&stats[C + c], ss);
    }
}

// ---------------------------------------------------------------- edge-parallel aggregation
// One wave per 64 contiguous dst-sorted positions; ONE EDGE PER LANE.
// Attr rows staged in LDS (round-7 verified win); broadcast via same-address
// ds_read_b64 on the DS pipe. This round:
//  - packed v_pk_fma_f32 dot (8 insts for the 16-FMA edge embedding)
//  - ballot-derived 64-bit boundary mask: in-loop segment check is pure SALU,
//    dst readlane only at actual flushes (~4/chunk vs 64)
//  - outer loop NOT unrolled (8-edge body) to bound code size / L1I pressure
__global__ __launch_bounds__(256) void edge_agg_kernel(
        const float* __restrict__ h, const float* __restrict__ ea,
        const int4* __restrict__ edge4,
        const float* __restrict__ We, const float* __restrict__ be,
        const float* __restrict__ tptr, const float* __restrict__ stats,
        const float* __restrict__ gamma, const float* __restrict__ beta,
        float* __restrict__ num, float* __restrict__ den) {
    __shared__ float sA[4 * 64 * LDS_STRIDE];    // 4 waves x 64 edges x 18 f = 18 KB
    int tid = threadIdx.x;
    int c  = tid & 63;                       // channel == lane
    int wv = tid >> 6;
    // BN folded: z = relu(h*sc + sb)
    float inv = 1.0f / (float)N_NODES;
    float mu  = stats[c] * inv;
    float var = stats[HDIM + c] * inv - mu * mu;
    float sc  = rsqrtf(var + 1e-5f) * gamma[c];
    float sb  = beta[c] - mu * sc;
    v2f w2[8];
#pragma unroll
    for (int k = 0; k < 8; k++) {
        w2[k].x = We[(2 * k) * HDIM + c];
        w2[k].y = We[(2 * k + 1) * HDIM + c];
    }
    float bc = be[c];
    float tl2 = (*tptr) * 1.4426950408889634f;   // t * log2(e)

    // this lane's own edge (position p in sorted order)
    int p = (blockIdx.x * 4 + wv) * 64 + c;      // grid sized so p < E always
    int4 pk = edge4[p];                          // one coalesced dwordx4
    int d_own = pk.x;
    int s_own = pk.y;
    int e     = pk.z;
    // stage own attr row to LDS
    float* myrow = &sA[(wv * 64 + c) * LDS_STRIDE];
    {
        const float4* ar = (const float4*)(ea + (size_t)e * EDIM);
        float4 a0 = ar[0], a1 = ar[1], a2 = ar[2], a3 = ar[3];
        myrow[0]=a0.x;  myrow[1]=a0.y;  myrow[2]=a0.z;  myrow[3]=a0.w;
        myrow[4]=a1.x;  myrow[5]=a1.y;  myrow[6]=a1.z;  myrow[7]=a1.w;
        myrow[8]=a2.x;  myrow[9]=a2.y;  myrow[10]=a2.z; myrow[11]=a2.w;
        myrow[12]=a3.x; myrow[13]=a3.y; myrow[14]=a3.z; myrow[15]=a3.w;
    }
    // boundary mask: bit u set iff dst changes at chunk position u (u>0)
    int dprev = __shfl_up(d_own, 1);
    unsigned long long bmask = __ballot(c > 0 && d_own != dprev);
    __syncthreads();                         // staging visible (per-wave use only)

    const float* wrow = &sA[(size_t)wv * 64 * LDS_STRIDE];
    float nacc = 0.f, dacc = 0.f;
    int cur_d = __builtin_amdgcn_readlane(d_own, 0);
#pragma unroll 1
    for (int jj = 0; jj < 64; jj += 8) {
        // issue 8 h-row gathers ahead (independent vector loads)
        float hv[8];
#pragma unroll
        for (int u = 0; u < 8; u++) {
            int su = __builtin_amdgcn_readlane(s_own, jj + u);
            hv[u] = h[(size_t)su * HDIM + c];
        }
#pragma unroll
        for (int u = 0; u < 8; u++) {
            if (bmask & (1ull << (jj + u))) {    // SALU test, wave-uniform
                atomicAdd(&num[(size_t)cur_d * HDIM + c], nacc);
                atomicAdd(&den[(size_t)cur_d * HDIM + c], dacc);
                nacc = 0.f; dacc = 0.f;
                cur_d = __builtin_amdgcn_readlane(d_own, jj + u);
            }
            // broadcast attr row via same-address ds_read_b64 (DS pipe)
            const v2f* arow = (const v2f*)&wrow[(jj + u) * LDS_STRIDE];
            v2f acc2 = {bc, 0.f};
#pragma unroll
            for (int k2 = 0; k2 < 8; k2++)
                acc2 += arow[k2] * w2[k2];       // v_pk_fma_f32
            float acc = acc2.x + acc2.y;
            float zv = fmaxf(hv[u] * sc + sb, 0.f);
            float m  = fmaxf(zv + acc, 0.f) + 1e-7f;
            float ex = exp2f(m * tl2);
            dacc += ex;
            nacc += ex * m;
        }
    }
    atomicAdd(&num[(size_t)cur_d * HDIM + c], nacc);
    atomicAdd(&den[(size_t)cur_d * HDIM + c], dacc);
}

// ---------------------------------------------------------------- MLP part 1
// Fused finalize: in = num/(den+eps) + relu(BN(h)); also self-cleans num/den
// to zero for the next layer (each idx touched exactly once).
__global__ __launch_bounds__(256) void mlp1_kernel(
        float* __restrict__ num, float* __restrict__ den,
        const float* __restrict__ h, const float* __restrict__ stats,
        const float* __restrict__ gamma, const float* __restrict__ beta,
        const float* __restrict__ W1, const float* __restrict__ b1,
        float* __restrict__ h1, int N) {
    __shared__ float sW[HDIM * 128];         // 32 KB
    __shared__ float srow[32 * 65];          // +1 pad breaks bank stride
    int tid = threadIdx.x;
    for (int i = tid; i < HDIM * 128; i += 256) sW[i] = W1[i];
    int base = blockIdx.x * 32;
    {
        int cc = tid & 63;                   // constant across the i-loop (256%64==0)
        float inv = 1.0f / (float)N_NODES;
        float mu  = stats[cc] * inv;
        float var = stats[HDIM + cc] * inv - mu * mu;
        float rs  = rsqrtf(var + 1e-5f);
        float ga  = gamma[cc], bb = beta[cc];
        for (int i = tid; i < 32 * HDIM; i += 256) {
            int r = i >> 6;
            int node = base + r;
            float v = 0.f;
            if (node < N) {
                size_t idx = (size_t)node * HDIM + cc;
                float hv = h[idx];
                float z  = fmaxf((hv - mu) * rs * ga + bb, 0.f);
                float nu = num[idx], de = den[idx];
                num[idx] = 0.f; den[idx] = 0.f;   // ready for next layer
                v = nu / (de + 1e-16f) + z;
            }
            srow[r * 65 + cc] = v;
        }
    }
    __syncthreads();
    int tx = tid & 31;                       // outputs 4*tx .. 4*tx+3
    int ty = tid >> 5;                       // nodes ty*4 .. ty*4+3
    float acc[4][4];
    float b0 = b1[4 * tx], bb1 = b1[4 * tx + 1], b2v = b1[4 * tx + 2], b3 = b1[4 * tx + 3];
#pragma unroll
    for (int j = 0; j < 4; j++) { acc[j][0] = b0; acc[j][1] = bb1; acc[j][2] = b2v; acc[j][3] = b3; }
#pragma unroll 8
    for (int k = 0; k < HDIM; k++) {
        float4 wv = *(const float4*)&sW[k * 128 + 4 * tx];
        float r0 = srow[(ty * 4 + 0) * 65 + k];
        float r1 = srow[(ty * 4 + 1) * 65 + k];
        float r2 = srow[(ty * 4 + 2) * 65 + k];
        float r3 = srow[(ty * 4 + 3) * 65 + k];
        acc[0][0] += r0 * wv.x; acc[0][1] += r0 * wv.y; acc[0][2] += r0 * wv.z; acc[0][3] += r0 * wv.w;
        acc[1][0] += r1 * wv.x; acc[1][1] += r1 * wv.y; acc[1][2] += r1 * wv.z; acc[1][3] += r1 * wv.w;
        acc[2][0] += r2 * wv.x; acc[2][1] += r2 * wv.y; acc[2][2] += r2 * wv.z; acc[2][3] += r2 * wv.w;
        acc[3][0] += r3 * wv.x; acc[3][1] += r3 * wv.y; acc[3][2] += r3 * wv.z; acc[3][3] += r3 * wv.w;
    }
#pragma unroll
    for (int j = 0; j < 4; j++) {
        int node = base + ty * 4 + j;
        if (node < N)
            *(float4*)&h1[(size_t)node * 128 + 4 * tx] =
                make_float4(acc[j][0], acc[j][1], acc[j][2], acc[j][3]);
    }
}

// ---------------------------------------------------------------- MLP part 2
__global__ __launch_bounds__(256) void mlp2_kernel(
        const float* __restrict__ h1, const float* __restrict__ stats,
        const float* __restrict__ mg, const float* __restrict__ mb,
        const float* __restrict__ W2, const float* __restrict__ b2,
        float* __restrict__ h, int N) {
    __shared__ float sW[128 * HDIM];         // 32 KB
    __shared__ float sact[32 * 129];         // 16.5 KB, +1 pad
    __shared__ float sbn[4 * 128];           // mu, rs, gamma, beta
    int tid = threadIdx.x;
    for (int i = tid; i < 128 * HDIM; i += 256) sW[i] = W2[i];
    if (tid < 128) {
        float inv = 1.0f / (float)N;
        float mu  = stats[tid] * inv;
        float var = stats[128 + tid] * inv - mu * mu;
        sbn[tid]       = mu;
        sbn[128 + tid] = rsqrtf(var + 1e-5f);
        sbn[256 + tid] = mg[tid];
        sbn[384 + tid] = mb[tid];
    }
    __syncthreads();
    int base = blockIdx.x * 32;
    for (int i = tid; i < 32 * 128; i += 256) {
        int r = i >> 7, o = i & 127;
        int node = base + r;
        float v = 0.f;
        if (node < N) {
            v = h1[(size_t)node * 128 + o];
            v = fmaxf((v - sbn[o]) * sbn[128 + o] * sbn[256 + o] + sbn[384 + o], 0.f);
        }
        sact[r * 129 + o] = v;
    }
    __syncthreads();
    int tx = tid & 15;                       // outputs 4*tx .. 4*tx+3
    int ty = tid >> 4;                       // nodes ty*2, ty*2+1
    float acc[2][4];
    float b0 = b2[4 * tx], bb1 = b2[4 * tx + 1], b2v = b2[4 * tx + 2], b3 = b2[4 * tx + 3];
    acc[0][0] = b0; acc[0][1] = bb1; acc[0][2] = b2v; acc[0][3] = b3;
    acc[1][0] = b0; acc[1][1] = bb1; acc[1][2] = b2v; acc[1][3] = b3;
#pragma unroll 8
    for (int k = 0; k < 128; k++) {
        float4 wv = *(const float4*)&sW[k * HDIM + 4 * tx];
        float r0 = sact[(ty * 2 + 0) * 129 + k];
        float r1 = sact[(ty * 2 + 1) * 129 + k];
        acc[0][0] += r0 * wv.x; acc[0][1] += r0 * wv.y; acc[0][2] += r0 * wv.z; acc[0][3] += r0 * wv.w;
        acc[1][0] += r1 * wv.x; acc[1][1] += r1 * wv.y; acc[1][2] += r1 * wv.z; acc[1][3] += r1 * wv.w;
    }
#pragma unroll
    for (int j = 0; j < 2; j++) {
        int node = base + ty * 2 + j;
        if (node < N) {
            float4* p = (float4*)&h[(size_t)node * HDIM + 4 * tx];
            float4 old = *p;
            *p = make_float4(old.x + acc[j][0], old.y + acc[j][1],
                             old.z + acc[j][2], old.w + acc[j][3]);
        }
    }
}

// ---------------------------------------------------------------- pool + head
__global__ void pool_out_kernel(const float* __restrict__ h, const int* __restrict__ gstart,
                                const float* __restrict__ Wo, const float* __restrict__ bo,
                                float* __restrict__ out, int N) {
    __shared__ float sp[HDIM];
    __shared__ float red[256];
    __shared__ float sW[HDIM * COUT];
    int g = blockIdx.x;
    int tid = threadIdx.x;
    for (int i = tid; i < HDIM * COUT; i += 256) sW[i] = Wo[i];
    int beg = gstart[g], end = gstart[g + 1];
    int c = tid & 63, r0 = tid >> 6;
    float s = 0.f;
    for (int r = beg + r0; r < end; r += 4) s += h[(size_t)r * HDIM + c];
    red[tid] = s;
    __syncthreads();
    if (tid < HDIM) {
        s = red[tid] + red[tid + 64] + red[tid + 128] + red[tid + 192];
        float cnt = (float)(end - beg);
        float pooled = s / fmaxf(cnt, 1.0f);
        sp[tid] = fmaxf(pooled, 0.0f);
    }
    __syncthreads();
    if (tid < COUT) {
        float acc = bo[tid];
#pragma unroll
        for (int k = 0; k < HDIM; k++) acc += sp[k] * sW[k * COUT + tid];
        out[g * COUT + tid] = acc;
    }
}

// ================================================================ launch
extern "C" void kernel_launch(void* const* d_in, const int* in_sizes, int n_in,
                              void* d_out, int out_size, void* d_ws, size_t ws_size,
                              hipStream_t stream) {
    (void)in_sizes; (void)n_in; (void)out_size; (void)ws_size;
    const float* x          = (const float*)d_in[0];
    const int*   eidx       = (const int*)  d_in[1];
    const float* eattr      = (const float*)d_in[2];
    const int*   batch      = (const int*)  d_in[3];
    const float* lin_in_w   = (const float*)d_in[4];
    const float* lin_in_b   = (const float*)d_in[5];
    const float* norm_gamma = (const float*)d_in[6];
    const float* norm_beta  = (const float*)d_in[7];
    const float* edge_w     = (const float*)d_in[8];
    const float* edge_b     = (const float*)d_in[9];
    const float* tparam     = (const float*)d_in[10];
    const float* mlp_w1     = (const float*)d_in[11];
    const float* mlp_b1     = (const float*)d_in[12];
    const float* mlp_gamma  = (const float*)d_in[13];
    const float* mlp_beta   = (const float*)d_in[14];
    const float* mlp_w2     = (const float*)d_in[15];
    const float* mlp_b2     = (const float*)d_in[16];
    const float* lin_out_w  = (const float*)d_in[17];
    const float* lin_out_b  = (const float*)d_in[18];
    float* out = (float*)d_out;

    const int* src = eidx;                   // edge_index[0]
    const int* dst = eidx + N_EDGES;         // edge_index[1]

    char* ws = (char*)d_ws;
    size_t off = 0;
    auto alloc = [&](size_t bytes) -> char* {
        char* p = ws + off;
        off = (off + bytes + 255) & ~(size_t)255;
        return p;
    };
    // zero-init region first (one memset covers histogram + all BN stats)
    int*   cnt     = (int*)  alloc((size_t)N_NODES * 4);
    float* statsA0 = (float*)alloc(128 * 4);
    float* statsB0 = (float*)alloc(256 * 4);
    float* statsA1 = (float*)alloc(128 * 4);
    float* statsB1 = (float*)alloc(256 * 4);
    size_t zero_bytes = off;
    int*   bsum    = (int*)  alloc(256 * 4);
    int*   offsets = (int*)  alloc((size_t)(N_NODES + 1) * 4);
    int*   cursor  = (int*)  alloc((size_t)N_NODES * 4);
    int4*  edge4   = (int4*) alloc((size_t)N_EDGES * 16);
    int*   gstart  = (int*)  alloc((size_t)(NGRAPH + 1) * 4);
    float* h       = (float*)alloc((size_t)N_NODES * HDIM * 4);
    float* num     = (float*)alloc((size_t)N_NODES * HDIM * 4);
    float* den     = (float*)alloc((size_t)N_NODES * HDIM * 4);   // contiguous after num
    float* h1      = (float*)alloc((size_t)N_NODES * 2 * HDIM * 4);

    hipMemsetAsync(d_ws, 0, zero_bytes, stream);
    // num+den zeroed once; mlp1 self-cleans them for the next layer
    hipMemsetAsync(num, 0, (size_t)N_NODES * HDIM * 4 * 2, stream);

    const int NB = (N_NODES + 255) / 256;    // 196 blocks
    hist_kernel      <<<(N_EDGES + 255) / 256, 256, 0, stream>>>(dst, cnt, N_EDGES);
    scan_part_kernel <<<NB, 256, 0, stream>>>(cnt, bsum, N_NODES);
    scan_top_kernel  <<<1, 256, 0, stream>>>(bsum, NB);
    scan_apply_kernel<<<NB, 256, 0, stream>>>(cnt, bsum, offsets, cursor, N_NODES);
    scatter_kernel   <<<(N_EDGES + 255) / 256, 256, 0, stream>>>(dst, src, cursor, edge4, N_EDGES);
    gstart_kernel    <<<NB, 256, 0, stream>>>(batch, gstart, N_NODES, NGRAPH);
    lin_in_kernel    <<<(N_NODES + 3) / 4, 256, 0, stream>>>(x, lin_in_w, lin_in_b, h, N_NODES);

    const int AGG_BLOCKS = N_EDGES / 256;    // 3125, exact (4 waves x 64 edges)

    float* statsA[2] = { statsA0, statsA1 };
    float* statsB[2] = { statsB0, statsB1 };
    for (int l = 0; l < 2; l++) {
        bn_stats_kernel<64><<<256, 256, 0, stream>>>(h, statsA[l], N_NODES);
        edge_agg_kernel<<<AGG_BLOCKS, 256, 0, stream>>>(
            h, eattr, edge4,
            edge_w + (size_t)l * EDIM * HDIM, edge_b + l * HDIM,
            tparam + l, statsA[l], norm_gamma + l * HDIM, norm_beta + l * HDIM,
            num, den);
        mlp1_kernel<<<(N_NODES + 31) / 32, 256, 0, stream>>>(
            num, den, h, statsA[l], norm_gamma + l * HDIM, norm_beta + l * HDIM,
            mlp_w1 + (size_t)l * HDIM * 2 * HDIM, mlp_b1 + l * 2 * HDIM, h1, N_NODES);
        bn_stats_kernel<128><<<256, 256, 0, stream>>>(h1, statsB[l], N_NODES);
        mlp2_kernel<<<(N_NODES + 31) / 32, 256, 0, stream>>>(
            h1, statsB[l], mlp_gamma + l * 2 * HDIM, mlp_beta + l * 2 * HDIM,
            mlp_w2 + (size_t)l * 2 * HDIM * HDIM, mlp_b2 + l * HDIM, h, N_NODES);
    }
    pool_out_kernel<<<NGRAPH, 256, 0, stream>>>(h, gstart, lin_out_w, lin_out_b, out, N_NODES);
}

// Round 10
// 627.298 us; speedup vs baseline: 1.3021x; 1.0072x over previous
//
#include <hip/hip_runtime.h>

#define N_NODES 50000
#define N_EDGES 800000
#define F_INP   32
#define HDIM    64
#define EDIM    16
#define COUT    40
#define NGRAPH  64
#define LDS_STRIDE 18   // floats per staged attr row: 16 + 2 pad (keeps b64 align, spreads banks)
#define CPAD    16      // cursor/cnt padding: 1 counter per 64B line (kills same-line atomic serialization)

typedef float v2f __attribute__((ext_vector_type(2)));

// ---------------------------------------------------------------- sort by dst
// 4 edges/thread: 4 independent atomic chains (MLP vs latency), int4 reads.
__global__ void hist_kernel(const int* __restrict__ dst, int* __restrict__ cnt, int E) {
    int base = (blockIdx.x * 256 + threadIdx.x) * 4;
    if (base >= E) return;                   // E % 4 == 0
    int4 d4 = *(const int4*)(dst + base);
    atomicAdd(&cnt[(size_t)d4.x * CPAD], 1);
    atomicAdd(&cnt[(size_t)d4.y * CPAD], 1);
    atomicAdd(&cnt[(size_t)d4.z * CPAD], 1);
    atomicAdd(&cnt[(size_t)d4.w * CPAD], 1);
}

// 3-stage scan over the PADDED cnt array (stride CPAD); cursor also padded.
__global__ void scan_part_kernel(const int* __restrict__ cnt, int* __restrict__ bsum, int n) {
    __shared__ int red[256];
    int tid = threadIdx.x;
    int idx = blockIdx.x * 256 + tid;
    red[tid] = (idx < n) ? cnt[(size_t)idx * CPAD] : 0;
    __syncthreads();
    for (int off = 128; off > 0; off >>= 1) {
        if (tid < off) red[tid] += red[tid + off];
        __syncthreads();
    }
    if (tid == 0) bsum[blockIdx.x] = red[0];
}

__global__ void scan_top_kernel(int* __restrict__ bsum, int nb) {
    __shared__ int tmp[256];
    int tid = threadIdx.x;
    int v = (tid < nb) ? bsum[tid] : 0;
    tmp[tid] = v;
    __syncthreads();
    for (int off = 1; off < 256; off <<= 1) {
        int x = (tid >= off) ? tmp[tid - off] : 0;
        __syncthreads();
        tmp[tid] += x;
        __syncthreads();
    }
    if (tid < nb) bsum[tid] = tmp[tid] - v;   // exclusive
}

__global__ void scan_apply_kernel(const int* __restrict__ cnt, const int* __restrict__ bsum,
                                  int* __restrict__ cursor, int n) {
    __shared__ int tmp[256];
    int tid = threadIdx.x;
    int idx = blockIdx.x * 256 + tid;
    int v = (idx < n) ? cnt[(size_t)idx * CPAD] : 0;
    tmp[tid] = v;
    __syncthreads();
    for (int off = 1; off < 256; off <<= 1) {
        int x = (tid >= off) ? tmp[tid - off] : 0;
        __syncthreads();
        tmp[tid] += x;
        __syncthreads();
    }
    int excl = tmp[tid] - v + bsum[blockIdx.x];
    if (idx < n) cursor[(size_t)idx * CPAD] = excl;
}

// scatter packed: one int4 (dst, src, edge_id, 0) per sorted position.
// 4 edges/thread for 4-deep independent atomic->store chains.
__global__ void scatter_kernel(const int* __restrict__ dst, const int* __restrict__ src,
                               int* __restrict__ cursor, int4* __restrict__ edge4, int E) {
    int base = (blockIdx.x * 256 + threadIdx.x) * 4;
    if (base >= E) return;                   // E % 4 == 0
    int4 d4 = *(const int4*)(dst + base);
    int4 s4 = *(const int4*)(src + base);
    int p0 = atomicAdd(&cursor[(size_t)d4.x * CPAD], 1);
    int p1 = atomicAdd(&cursor[(size_t)d4.y * CPAD], 1);
    int p2 = atomicAdd(&cursor[(size_t)d4.z * CPAD], 1);
    int p3 = atomicAdd(&cursor[(size_t)d4.w * CPAD], 1);
    edge4[p0] = make_int4(d4.x, s4.x, base + 0, 0);
    edge4[p1] = make_int4(d4.y, s4.y, base + 1, 0);
    edge4[p2] = make_int4(d4.z, s4.z, base + 2, 0);
    edge4[p3] = make_int4(d4.w, s4.w, base + 3, 0);
}

// batch is sorted ascending; find graph start offsets
__global__ void gstart_kernel(const int* __restrict__ batch, int* __restrict__ gstart,
                              int N, int G) {
    int n = blockIdx.x * 256 + threadIdx.x;
    if (n >= N) return;
    int g  = batch[n];
    int gp = (n == 0) ? -1 : batch[n - 1];
    for (int gg = gp + 1; gg <= g; gg++) gstart[gg] = n;
    if (n == N - 1) {
        for (int gg = g + 1; gg <= G; gg++) gstart[gg] = N;
    }
}

// ---------------------------------------------------------------- input linear
__global__ void lin_in_kernel(const float* __restrict__ x, const float* __restrict__ W,
                              const float* __restrict__ b, float* __restrict__ h, int N) {
    int tid = threadIdx.x;
    int c = tid & 63;
    float w[F_INP];
#pragma unroll
    for (int k = 0; k < F_INP; k++) w[k] = W[k * HDIM + c];
    int node = blockIdx.x * 4 + (tid >> 6);
    if (node >= N) return;
    const float4* xr = (const float4*)(x + (size_t)node * F_INP);
    float acc = b[c];
#pragma unroll
    for (int k4 = 0; k4 < F_INP / 4; k4++) {
        float4 xv = xr[k4];
        acc += xv.x * w[k4 * 4 + 0] + xv.y * w[k4 * 4 + 1]
             + xv.z * w[k4 * 4 + 2] + xv.w * w[k4 * 4 + 3];
    }
    h[(size_t)node * HDIM + c] = acc;
}

// ---------------------------------------------------------------- BN stats
template <int C>
__global__ void bn_stats_kernel(const float* __restrict__ x, float* __restrict__ stats, int N) {
    const int RPB = 256 / C;
    int tid = threadIdx.x;
    int c = tid % C;
    int row0 = blockIdx.x * RPB + tid / C;
    int stride = gridDim.x * RPB;
    float s = 0.f, ss = 0.f;
    for (int r = row0; r < N; r += stride) {
        float v = x[(size_t)r * C + c];
        s += v; ss += v * v;
    }
    __shared__ float ls[256], lss[256];
    ls[tid] = s; lss[tid] = ss;
    __syncthreads();
    if (tid < C) {
        for (int k = 1; k < RPB; k++) { s += ls[tid + k * C]; ss += lss[tid + k * C]; }
        atomicAdd(&stats[c], s);
        atomicAdd(&stats[C + c], ss);
    }
}

// ---------------------------------------------------------------- edge-parallel aggregation
// One wave per 64 contiguous dst-sorted positions; ONE EDGE PER LANE.
// Attr rows staged in LDS; broadcast via same-address ds_read_b64 (DS pipe).
// pk_fma dot, ballot boundary mask (SALU in-loop test), 8-edge rolled body.
// (round-8 verified structure, unchanged)
__global__ __launch_bounds__(256) void edge_agg_kernel(
        const float* __restrict__ h, const float* __restrict__ ea,
        const int4* __restrict__ edge4,
        const float* __restrict__ We, const float* __restrict__ be,
        const float* __restrict__ tptr, const float* __restrict__ stats,
        const float* __restrict__ gamma, const float* __restrict__ beta,
        float* __restrict__ num, float* __restrict__ den) {
    __shared__ float sA[4 * 64 * LDS_STRIDE];    // 4 waves x 64 edges x 18 f = 18 KB
    int tid = threadIdx.x;
    int c  = tid & 63;                       // channel == lane
    int wv = tid >> 6;
    // BN folded: z = relu(h*sc + sb)
    float inv = 1.0f / (float)N_NODES;
    float mu  = stats[c] * inv;
    float var = stats[HDIM + c] * inv - mu * mu;
    float sc  = rsqrtf(var + 1e-5f) * gamma[c];
    float sb  = beta[c] - mu * sc;
    v2f w2[8];
#pragma unroll
    for (int k = 0; k < 8; k++) {
        w2[k].x = We[(2 * k) * HDIM + c];
        w2[k].y = We[(2 * k + 1) * HDIM + c];
    }
    float bc = be[c];
    float tl2 = (*tptr) * 1.4426950408889634f;   // t * log2(e)

    // this lane's own edge (position p in sorted order)
    int p = (blockIdx.x * 4 + wv) * 64 + c;      // grid sized so p < E always
    int4 pk = edge4[p];                          // one coalesced dwordx4
    int d_own = pk.x;
    int s_own = pk.y;
    int e     = pk.z;
    // stage own attr row to LDS
    float* myrow = &sA[(wv * 64 + c) * LDS_STRIDE];
    {
        const float4* ar = (const float4*)(ea + (size_t)e * EDIM);
        float4 a0 = ar[0], a1 = ar[1], a2 = ar[2], a3 = ar[3];
        myrow[0]=a0.x;  myrow[1]=a0.y;  myrow[2]=a0.z;  myrow[3]=a0.w;
        myrow[4]=a1.x;  myrow[5]=a1.y;  myrow[6]=a1.z;  myrow[7]=a1.w;
        myrow[8]=a2.x;  myrow[9]=a2.y;  myrow[10]=a2.z; myrow[11]=a2.w;
        myrow[12]=a3.x; myrow[13]=a3.y; myrow[14]=a3.z; myrow[15]=a3.w;
    }
    // boundary mask: bit u set iff dst changes at chunk position u (u>0)
    int dprev = __shfl_up(d_own, 1);
    unsigned long long bmask = __ballot(c > 0 && d_own != dprev);
    __syncthreads();                         // staging visible (per-wave use only)

    const float* wrow = &sA[(size_t)wv * 64 * LDS_STRIDE];
    float nacc = 0.f, dacc = 0.f;
    int cur_d = __builtin_amdgcn_readlane(d_own, 0);
#pragma unroll 1
    for (int jj = 0; jj < 64; jj += 8) {
        // issue 8 h-row gathers ahead (independent vector loads)
        float hv[8];
#pragma unroll
        for (int u = 0; u < 8; u++) {
            int su = __builtin_amdgcn_readlane(s_own, jj + u);
            hv[u] = h[(size_t)su * HDIM + c];
        }
#pragma unroll
        for (int u = 0; u < 8; u++) {
            if (bmask & (1ull << (jj + u))) {    // SALU test, wave-uniform
                atomicAdd(&num[(size_t)cur_d * HDIM + c], nacc);
                atomicAdd(&den[(size_t)cur_d * HDIM + c], dacc);
                nacc = 0.f; dacc = 0.f;
                cur_d = __builtin_amdgcn_readlane(d_own, jj + u);
            }
            // broadcast attr row via same-address ds_read_b64 (DS pipe)
            const v2f* arow = (const v2f*)&wrow[(jj + u) * LDS_STRIDE];
            v2f acc2 = {bc, 0.f};
#pragma unroll
            for (int k2 = 0; k2 < 8; k2++)
                acc2 += arow[k2] * w2[k2];       // v_pk_fma_f32
            float acc = acc2.x + acc2.y;
            float zv = fmaxf(hv[u] * sc + sb, 0.f);
            float m  = fmaxf(zv + acc, 0.f) + 1e-7f;
            float ex = exp2f(m * tl2);
            dacc += ex;
            nacc += ex * m;
        }
    }
    atomicAdd(&num[(size_t)cur_d * HDIM + c], nacc);
    atomicAdd(&den[(size_t)cur_d * HDIM + c], dacc);
}

// ---------------------------------------------------------------- MLP part 1
// Fused finalize: in = num/(den+eps) + relu(BN(h)); also self-cleans num/den
// to zero for the next layer (each idx touched exactly once).
__global__ __launch_bounds__(256) void mlp1_kernel(
        float* __restrict__ num, float* __restrict__ den,
        const float* __restrict__ h, const float* __restrict__ stats,
        const float* __restrict__ gamma, const float* __restrict__ beta,
        const float* __restrict__ W1, const float* __restrict__ b1,
        float* __restrict__ h1, int N) {
    __shared__ float sW[HDIM * 128];         // 32 KB
    __shared__ float srow[32 * 65];          // +1 pad breaks bank stride
    int tid = threadIdx.x;
    for (int i = tid; i < HDIM * 128; i += 256) sW[i] = W1[i];
    int base = blockIdx.x * 32;
    {
        int cc = tid & 63;                   // constant across the i-loop (256%64==0)
        float inv = 1.0f / (float)N_NODES;
        float mu  = stats[cc] * inv;
        float var = stats[HDIM + cc] * inv - mu * mu;
        float rs  = rsqrtf(var + 1e-5f);
        float ga  = gamma[cc], bb = beta[cc];
        for (int i = tid; i < 32 * HDIM; i += 256) {
            int r = i >> 6;
            int node = base + r;
            float v = 0.f;
            if (node < N) {
                size_t idx = (size_t)node * HDIM + cc;
                float hv = h[idx];
                float z  = fmaxf((hv - mu) * rs * ga + bb, 0.f);
                float nu = num[idx], de = den[idx];
                num[idx] = 0.f; den[idx] = 0.f;   // ready for next layer
                v = nu / (de + 1e-16f) + z;
            }
            srow[r * 65 + cc] = v;
        }
    }
    __syncthreads();
    int tx = tid & 31;                       // outputs 4*tx .. 4*tx+3
    int ty = tid >> 5;                       // nodes ty*4 .. ty*4+3
    float acc[4][4];
    float b0 = b1[4 * tx], bb1 = b1[4 * tx + 1], b2v = b1[4 * tx + 2], b3 = b1[4 * tx + 3];
#pragma unroll
    for (int j = 0; j < 4; j++) { acc[j][0] = b0; acc[j][1] = bb1; acc[j][2] = b2v; acc[j][3] = b3; }
#pragma unroll 8
    for (int k = 0; k < HDIM; k++) {
        float4 wv = *(const float4*)&sW[k * 128 + 4 * tx];
        float r0 = srow[(ty * 4 + 0) * 65 + k];
        float r1 = srow[(ty * 4 + 1) * 65 + k];
        float r2 = srow[(ty * 4 + 2) * 65 + k];
        float r3 = srow[(ty * 4 + 3) * 65 + k];
        acc[0][0] += r0 * wv.x; acc[0][1] += r0 * wv.y; acc[0][2] += r0 * wv.z; acc[0][3] += r0 * wv.w;
        acc[1][0] += r1 * wv.x; acc[1][1] += r1 * wv.y; acc[1][2] += r1 * wv.z; acc[1][3] += r1 * wv.w;
        acc[2][0] += r2 * wv.x; acc[2][1] += r2 * wv.y; acc[2][2] += r2 * wv.z; acc[2][3] += r2 * wv.w;
        acc[3][0] += r3 * wv.x; acc[3][1] += r3 * wv.y; acc[3][2] += r3 * wv.z; acc[3][3] += r3 * wv.w;
    }
#pragma unroll
    for (int j = 0; j < 4; j++) {
        int node = base + ty * 4 + j;
        if (node < N)
            *(float4*)&h1[(size_t)node * 128 + 4 * tx] =
                make_float4(acc[j][0], acc[j][1], acc[j][2], acc[j][3]);
    }
}

// ---------------------------------------------------------------- MLP part 2
__global__ __launch_bounds__(256) void mlp2_kernel(
        const float* __restrict__ h1, const float* __restrict__ stats,
        const float* __restrict__ mg, const float* __restrict__ mb,
        const float* __restrict__ W2, const float* __restrict__ b2,
        float* __restrict__ h, int N) {
    __shared__ float sW[128 * HDIM];         // 32 KB
    __shared__ float sact[32 * 129];         // 16.5 KB, +1 pad
    __shared__ float sbn[4 * 128];           // mu, rs, gamma, beta
    int tid = threadIdx.x;
    for (int i = tid; i < 128 * HDIM; i += 256) sW[i] = W2[i];
    if (tid < 128) {
        float inv = 1.0f / (float)N;
        float mu  = stats[tid] * inv;
        float var = stats[128 + tid] * inv - mu * mu;
        sbn[tid]       = mu;
        sbn[128 + tid] = rsqrtf(var + 1e-5f);
        sbn[256 + tid] = mg[tid];
        sbn[384 + tid] = mb[tid];
    }
    __syncthreads();
    int base = blockIdx.x * 32;
    for (int i = tid; i < 32 * 128; i += 256) {
        int r = i >> 7, o = i & 127;
        int node = base + r;
        float v = 0.f;
        if (node < N) {
            v = h1[(size_t)node * 128 + o];
            v = fmaxf((v - sbn[o]) * sbn[128 + o] * sbn[256 + o] + sbn[384 + o], 0.f);
        }
        sact[r * 129 + o] = v;
    }
    __syncthreads();
    int tx = tid & 15;                       // outputs 4*tx .. 4*tx+3
    int ty = tid >> 4;                       // nodes ty*2, ty*2+1
    float acc[2][4];
    float b0 = b2[4 * tx], bb1 = b2[4 * tx + 1], b2v = b2[4 * tx + 2], b3 = b2[4 * tx + 3];
    acc[0][0] = b0; acc[0][1] = bb1; acc[0][2] = b2v; acc[0][3] = b3;
    acc[1][0] = b0; acc[1][1] = bb1; acc[1][2] = b2v; acc[1][3] = b3;
#pragma unroll 8
    for (int k = 0; k < 128; k++) {
        float4 wv = *(const float4*)&sW[k * HDIM + 4 * tx];
        float r0 = sact[(ty * 2 + 0) * 129 + k];
        float r1 = sact[(ty * 2 + 1) * 129 + k];
        acc[0][0] += r0 * wv.x; acc[0][1] += r0 * wv.y; acc[0][2] += r0 * wv.z; acc[0][3] += r0 * wv.w;
        acc[1][0] += r1 * wv.x; acc[1][1] += r1 * wv.y; acc[1][2] += r1 * wv.z; acc[1][3] += r1 * wv.w;
    }
#pragma unroll
    for (int j = 0; j < 2; j++) {
        int node = base + ty * 2 + j;
        if (node < N) {
            float4* p = (float4*)&h[(size_t)node * HDIM + 4 * tx];
            float4 old = *p;
            *p = make_float4(old.x + acc[j][0], old.y + acc[j][1],
                             old.z + acc[j][2], old.w + acc[j][3]);
        }
    }
}

// ---------------------------------------------------------------- pool + head
__global__ void pool_out_kernel(const float* __restrict__ h, const int* __restrict__ gstart,
                                const float* __restrict__ Wo, const float* __restrict__ bo,
                                float* __restrict__ out, int N) {
    __shared__ float sp[HDIM];
    __shared__ float red[256];
    __shared__ float sW[HDIM * COUT];
    int g = blockIdx.x;
    int tid = threadIdx.x;
    for (int i = tid; i < HDIM * COUT; i += 256) sW[i] = Wo[i];
    int beg = gstart[g], end = gstart[g + 1];
    int c = tid & 63, r0 = tid >> 6;
    float s = 0.f;
    for (int r = beg + r0; r < end; r += 4) s += h[(size_t)r * HDIM + c];
    red[tid] = s;
    __syncthreads();
    if (tid < HDIM) {
        s = red[tid] + red[tid + 64] + red[tid + 128] + red[tid + 192];
        float cnt = (float)(end - beg);
        float pooled = s / fmaxf(cnt, 1.0f);
        sp[tid] = fmaxf(pooled, 0.0f);
    }
    __syncthreads();
    if (tid < COUT) {
        float acc = bo[tid];
#pragma unroll
        for (int k = 0; k < HDIM; k++) acc += sp[k] * sW[k * COUT + tid];
        out[g * COUT + tid] = acc;
    }
}

// ================================================================ launch
extern "C" void kernel_launch(void* const* d_in, const int* in_sizes, int n_in,
                              void* d_out, int out_size, void* d_ws, size_t ws_size,
                              hipStream_t stream) {
    (void)in_sizes; (void)n_in; (void)out_size; (void)ws_size;
    const float* x          = (const float*)d_in[0];
    const int*   eidx       = (const int*)  d_in[1];
    const float* eattr      = (const float*)d_in[2];
    const int*   batch      = (const int*)  d_in[3];
    const float* lin_in_w   = (const float*)d_in[4];
    const float* lin_in_b   = (const float*)d_in[5];
    const float* norm_gamma = (const float*)d_in[6];
    const float* norm_beta  = (const float*)d_in[7];
    const float* edge_w     = (const float*)d_in[8];
    const float* edge_b     = (const float*)d_in[9];
    const float* tparam     = (const float*)d_in[10];
    const float* mlp_w1     = (const float*)d_in[11];
    const float* mlp_b1     = (const float*)d_in[12];
    const float* mlp_gamma  = (const float*)d_in[13];
    const float* mlp_beta   = (const float*)d_in[14];
    const float* mlp_w2     = (const float*)d_in[15];
    const float* mlp_b2     = (const float*)d_in[16];
    const float* lin_out_w  = (const float*)d_in[17];
    const float* lin_out_b  = (const float*)d_in[18];
    float* out = (float*)d_out;

    const int* src = eidx;                   // edge_index[0]
    const int* dst = eidx + N_EDGES;         // edge_index[1]

    char* ws = (char*)d_ws;
    size_t off = 0;
    auto alloc = [&](size_t bytes) -> char* {
        char* p = ws + off;
        off = (off + bytes + 255) & ~(size_t)255;
        return p;
    };
    // stats first (zero region)
    float* statsA0 = (float*)alloc(128 * 4);
    float* statsB0 = (float*)alloc(256 * 4);
    float* statsA1 = (float*)alloc(128 * 4);
    float* statsB1 = (float*)alloc(256 * 4);
    size_t zero_bytes = off;
    int*   bsum    = (int*)  alloc(256 * 4);
    int4*  edge4   = (int4*) alloc((size_t)N_EDGES * 16);
    int*   gstart  = (int*)  alloc((size_t)(NGRAPH + 1) * 4);
    float* h       = (float*)alloc((size_t)N_NODES * HDIM * 4);
    float* num     = (float*)alloc((size_t)N_NODES * HDIM * 4);
    float* den     = (float*)alloc((size_t)N_NODES * HDIM * 4);   // contiguous after num
    float* h1      = (float*)alloc((size_t)N_NODES * 2 * HDIM * 4);
    // Padded cnt/cursor (3.2 MB each) ALIASED into h1: the sort pipeline
    // completes before mlp1 ever writes h1, and h1 (25.6 MB) >= 6.4 MB.
    // Keeps total workspace at the proven ~77 MB footprint (round-9 risk:
    // +6.4 MB of fresh allocs may have overflowed ws_size -> container crash).
    int*   cnt     = (int*)h1;
    int*   cursor  = (int*)((char*)h1 + (size_t)N_NODES * CPAD * 4);

    hipMemsetAsync(d_ws, 0, zero_bytes, stream);                       // stats
    hipMemsetAsync(cnt, 0, (size_t)N_NODES * CPAD * 4, stream);        // padded histogram
    // num+den zeroed once; mlp1 self-cleans them for the next layer
    hipMemsetAsync(num, 0, (size_t)N_NODES * HDIM * 4 * 2, stream);

    const int NB = (N_NODES + 255) / 256;    // 196 blocks
    const int EB4 = (N_EDGES / 4 + 255) / 256;   // 782 blocks (4 edges/thread)
    hist_kernel      <<<EB4, 256, 0, stream>>>(dst, cnt, N_EDGES);
    scan_part_kernel <<<NB, 256, 0, stream>>>(cnt, bsum, N_NODES);
    scan_top_kernel  <<<1, 256, 0, stream>>>(bsum, NB);
    scan_apply_kernel<<<NB, 256, 0, stream>>>(cnt, bsum, cursor, N_NODES);
    scatter_kernel   <<<EB4, 256, 0, stream>>>(dst, src, cursor, edge4, N_EDGES);
    gstart_kernel    <<<NB, 256, 0, stream>>>(batch, gstart, N_NODES, NGRAPH);
    lin_in_kernel    <<<(N_NODES + 3) / 4, 256, 0, stream>>>(x, lin_in_w, lin_in_b, h, N_NODES);

    const int AGG_BLOCKS = N_EDGES / 256;    // 3125, exact (4 waves x 64 edges)

    float* statsA[2] = { statsA0, statsA1 };
    float* statsB[2] = { statsB0, statsB1 };
    for (int l = 0; l < 2; l++) {
        bn_stats_kernel<64><<<256, 256, 0, stream>>>(h, statsA[l], N_NODES);
        edge_agg_kernel<<<AGG_BLOCKS, 256, 0, stream>>>(
            h, eattr, edge4,
            edge_w + (size_t)l * EDIM * HDIM, edge_b + l * HDIM,
            tparam + l, statsA[l], norm_gamma + l * HDIM, norm_beta + l * HDIM,
            num, den);
        mlp1_kernel<<<(N_NODES + 31) / 32, 256, 0, stream>>>(
            num, den, h, statsA[l], norm_gamma + l * HDIM, norm_beta + l * HDIM,
            mlp_w1 + (size_t)l * HDIM * 2 * HDIM, mlp_b1 + l * 2 * HDIM, h1, N_NODES);
        bn_stats_kernel<128><<<256, 256, 0, stream>>>(h1, statsB[l], N_NODES);
        mlp2_kernel<<<(N_NODES + 31) / 32, 256, 0, stream>>>(
            h1, statsB[l], mlp_gamma + l * 2 * HDIM, mlp_beta + l * 2 * HDIM,
            mlp_w2 + (size_t)l * 2 * HDIM * HDIM, mlp_b2 + l * HDIM, h, N_NODES);
    }
    pool_out_kernel<<<NGRAPH, 256, 0, stream>>>(h, gstart, lin_out_w, lin_out_b, out, N_NODES);
}